// Round 10
// baseline (598.795 us; speedup 1.0000x reference)
//
#include <hip/hip_runtime.h>
#include <math.h>

typedef unsigned short ushort_t;
typedef unsigned int uint_t;
typedef __attribute__((ext_vector_type(8))) short bf16x8;
typedef __attribute__((ext_vector_type(4))) float f32x4;

#define NPTS 65536
#define NSAMP 16
#define CH 64
#define NROWS (NPTS*NSAMP)
#define NTILES (NROWS/16)
#define BN_EPS 1e-5f

// stat banks: 32 banks x 160 floats
#define BANKS 32
#define BANK_STRIDE 160
#define BOFF_S3S 0     // sum3[3] @0, sq3[3] @3
#define BOFF_S64S 16   // sum64[64] @16
#define BOFF_S64Q 80   // sq64[64] @80
#define BOFF_S8S 144   // sum8[8]
#define BOFF_S8Q 152   // sq8[8]
// finalized scale/shift
#define OFF_F3   5120  // scale3[3], shift3[3]
#define OFF_F64  5128  // scale64[64], shift64[64]
#define OFF_F8   5256  // scale8[8], shift8[8]
// big arrays (float offsets)
#define OFF_XQH  5376
#define OFF_XKH  (OFF_XQH + NPTS*CH/2)
#define OFF_XVH  (OFF_XKH + NPTS*CH/2)
#define OFF_PR1  (OFF_XVH + NPTS*CH/2)
#define OFF_W2   (OFF_PR1 + (size_t)NROWS*3)
// total ~17.8M floats ~71MB

__device__ __forceinline__ float wave_sum(float v){
#pragma unroll
  for (int m = 32; m > 0; m >>= 1) v += __shfl_xor(v, m);
  return v;
}
__device__ __forceinline__ ushort_t f2bf(float f){
  uint_t u = __float_as_uint(f);
  u += 0x7fffu + ((u >> 16) & 1u);
  return (ushort_t)(u >> 16);
}
__device__ __forceinline__ float bf2f(ushort_t h){
  return __uint_as_float(((uint_t)h) << 16);
}

__global__ void k_zero(float* __restrict__ ws){
  for (int i = threadIdx.x; i < 5376; i += 256) ws[i] = 0.0f;
}

// q/k/v projections -> bf16. 8 threads per point: thread (n, cg) computes
// channels cg*8..cg*8+7 and stores ONE uint4 (16B) -> wave store = 1024B
// fully contiguous (fixes the 8x HBM write amplification of the row layout).
__global__ __launch_bounds__(256) void k_proj(const float* __restrict__ x,
    const float* __restrict__ W0, const float* __restrict__ b0,
    const float* __restrict__ W1, const float* __restrict__ b1,
    const float* __restrict__ W2, const float* __restrict__ b2,
    ushort_t* __restrict__ xqh, ushort_t* __restrict__ xkh, ushort_t* __restrict__ xvh)
{
  int t = blockIdx.x * 256 + threadIdx.x;
  int n  = t >> 3;     // point
  int cg = t & 7;      // channel group of 8 outputs
  const float* W; const float* b; ushort_t* outp;
  if (blockIdx.y == 0)      { W = W0; b = b0; outp = xqh; }
  else if (blockIdx.y == 1) { W = W1; b = b1; outp = xkh; }
  else                      { W = W2; b = b2; outp = xvh; }

  float4 xr[16];
  const float4* xp = (const float4*)(x + (size_t)n * CH);
#pragma unroll
  for (int i = 0; i < 16; i++) xr[i] = xp[i];

  uint_t res[4];
#pragma unroll
  for (int op = 0; op < 4; op++){
    float a[2];
#pragma unroll
    for (int oo = 0; oo < 2; oo++){
      int o = cg*8 + op*2 + oo;
      float acc = b[o];
      const float4* wp = (const float4*)(W + o * CH);
#pragma unroll
      for (int i = 0; i < 16; i++){
        float4 w4 = wp[i];
        acc += xr[i].x * w4.x + xr[i].y * w4.y + xr[i].z * w4.z + xr[i].w * w4.w;
      }
      a[oo] = acc;
    }
    res[op] = (uint_t)f2bf(a[0]) | ((uint_t)f2bf(a[1]) << 16);
  }
  uint4 st; st.x = res[0]; st.y = res[1]; st.z = res[2]; st.w = res[3];
  *(uint4*)(outp + (size_t)n * CH + cg*8) = st;
}

// p_r stage 1 (Linear(3,3)) + BN3 partial sums
__global__ __launch_bounds__(256) void k_pr1(const float* __restrict__ p,
    const int* __restrict__ idx, const float* __restrict__ Wp1,
    const float* __restrict__ bp1, float* __restrict__ ws)
{
  float* pr1 = ws + OFF_PR1;
  float w00=Wp1[0],w01=Wp1[1],w02=Wp1[2];
  float w10=Wp1[3],w11=Wp1[4],w12=Wp1[5];
  float w20=Wp1[6],w21=Wp1[7],w22=Wp1[8];
  float b0=bp1[0],b1=bp1[1],b2=bp1[2];
  float s0=0,s1=0,s2=0,q0=0,q1=0,q2=0;
  int r0 = blockIdx.x*256 + threadIdx.x;
#pragma unroll
  for (int it = 0; it < 4; it++){
    int r = r0 + it*262144;
    int n = r >> 4;
    int iv = idx[r];
    float dx = p[iv*3+0] - p[n*3+0];
    float dy = p[iv*3+1] - p[n*3+1];
    float dz = p[iv*3+2] - p[n*3+2];
    float v0 = b0 + dx*w00 + dy*w01 + dz*w02;
    float v1 = b1 + dx*w10 + dy*w11 + dz*w12;
    float v2 = b2 + dx*w20 + dy*w21 + dz*w22;
    pr1[(size_t)r*3+0]=v0; pr1[(size_t)r*3+1]=v1; pr1[(size_t)r*3+2]=v2;
    s0+=v0; s1+=v1; s2+=v2;
    q0+=v0*v0; q1+=v1*v1; q2+=v2*v2;
  }
  s0=wave_sum(s0); s1=wave_sum(s1); s2=wave_sum(s2);
  q0=wave_sum(q0); q1=wave_sum(q1); q2=wave_sum(q2);
  __shared__ float lds[4][6];
  int lane = threadIdx.x & 63, wv = threadIdx.x >> 6;
  if (lane == 0){
    lds[wv][0]=s0; lds[wv][1]=s1; lds[wv][2]=s2;
    lds[wv][3]=q0; lds[wv][4]=q1; lds[wv][5]=q2;
  }
  __syncthreads();
  if (threadIdx.x < 6){
    float v = lds[0][threadIdx.x]+lds[1][threadIdx.x]+lds[2][threadIdx.x]+lds[3][threadIdx.x];
    atomicAdd(ws + (blockIdx.x & (BANKS-1))*BANK_STRIDE + BOFF_S3S + threadIdx.x, v);
  }
}

// BN finalize from banked sums
__global__ void k_finalize(const float* __restrict__ ws, float* __restrict__ outf,
                           const float* __restrict__ g, const float* __restrict__ beta,
                           int nch, int sum_off, int sq_off)
{
  int t = threadIdx.x;
  if (t < nch){
    float s = 0.f, q = 0.f;
    for (int b = 0; b < BANKS; b++){
      s += ws[b*BANK_STRIDE + sum_off + t];
      q += ws[b*BANK_STRIDE + sq_off + t];
    }
    float invM = 1.0f / (float)NROWS;
    float mean = s * invM;
    float var  = q * invM - mean * mean;
    float rs   = rsqrtf(var + BN_EPS);
    float sc   = g[t] * rs;
    outf[t] = sc;
    outf[nch + t] = beta[t] - mean * sc;
  }
}

// BN64 stats over w_pre = xk[idx] - xq + p_r2.
// Wave-unit = 8 tiles x one channel-half, FULLY FLATTENED: 8 idx + 24 pr1
// loads issue, then all 8 xk-gathers in flight (2 latency exposures).
// xq broadcasts folded into compute (L2-resident). Cross-wave LDS combine
// cuts atomics 4x vs round 8: 128 lane-atomics/block.
__global__ __launch_bounds__(256) void k_stats64(const int* __restrict__ idx,
    const ushort_t* __restrict__ xqh, const ushort_t* __restrict__ xkh,
    const float* __restrict__ pr1, const float* __restrict__ f3,
    const float* __restrict__ Wp2, const float* __restrict__ bp2,
    float* __restrict__ ws)
{
  __shared__ float lds[4][64];
  int lane = threadIdx.x & 63;
  int r16 = lane & 15, g = lane >> 4;
  int wv = threadIdx.x >> 6;
  int uid = __builtin_amdgcn_readfirstlane(blockIdx.x*4 + wv);
  int half = uid & 1;                // == wv & 1 (blockIdx*4 is even)
  int t0 = (uid >> 1) * 8;           // 8 tiles per wave-unit
  int hoff = half * 32;

  // phase A: per-lane idx + pr1 rows (all independent, issue together)
  int ivv[8];
#pragma unroll
  for (int t = 0; t < 8; t++) ivv[t] = idx[(t0+t)*16 + r16];
  float pa[8], pb[8], pc[8];
#pragma unroll
  for (int t = 0; t < 8; t++){
    int r = (t0+t)*16 + r16;
    pa[t] = pr1[(size_t)r*3+0];
    pb[t] = pr1[(size_t)r*3+1];
    pc[t] = pr1[(size_t)r*3+2];
  }
  // phase B: all 8 gathers in flight
  bf16x8 kk[8];
#pragma unroll
  for (int t = 0; t < 8; t++)
    kk[t] = *(const bf16x8*)(xkh + (size_t)ivv[t]*CH + hoff + g*8);

  // per-lane channel constants
  float sc0=f3[0], sc1=f3[1], sc2=f3[2], sh0=f3[3], sh1=f3[4], sh2=f3[5];
  float wpa[8], wpb[8], wpc[8], bpv[8];
#pragma unroll
  for (int j = 0; j < 8; j++){
    int c = hoff + g*8 + j;
    wpa[j] = Wp2[c*3+0]; wpb[j] = Wp2[c*3+1]; wpc[j] = Wp2[c*3+2];
    bpv[j] = bp2[c];
  }

  float accs[8], accq[8];
#pragma unroll
  for (int j = 0; j < 8; j++){ accs[j]=0.f; accq[j]=0.f; }

#pragma unroll
  for (int t = 0; t < 8; t++){
    bf16x8 qq = *(const bf16x8*)(xqh + (size_t)(t0+t)*CH + hoff + g*8);
    float rb0 = fmaxf(fmaf(pa[t], sc0, sh0), 0.f);
    float rb1 = fmaxf(fmaf(pb[t], sc1, sh1), 0.f);
    float rb2 = fmaxf(fmaf(pc[t], sc2, sh2), 0.f);
#pragma unroll
    for (int j = 0; j < 8; j++){
      float w = bf2f((ushort_t)kk[t][j]) - bf2f((ushort_t)qq[j])
              + bpv[j] + rb0*wpa[j] + rb1*wpb[j] + rb2*wpc[j];
      accs[j] += w; accq[j] = fmaf(w, w, accq[j]);
    }
  }

  // reduce over r16 (lane bits 0..3)
#pragma unroll
  for (int j = 0; j < 8; j++){
#pragma unroll
    for (int m = 1; m <= 8; m <<= 1){
      accs[j] += __shfl_xor(accs[j], m);
      accq[j] += __shfl_xor(accq[j], m);
    }
  }
  // per-wave partials -> LDS (lanes r16==0: g=0..3 each hold 8 channels)
  if (r16 == 0){
#pragma unroll
    for (int j = 0; j < 8; j++){
      lds[wv][g*8 + j]      = accs[j];
      lds[wv][32 + g*8 + j] = accq[j];
    }
  }
  __syncthreads();
  // combine waves sharing the same half (wv0&2 -> half0, wv1&3 -> half1)
  int t = threadIdx.x;
  if (t < 128){
    int h = t >> 6;          // 0: half0, 1: half1
    int u = t & 63;          // 0..31 sums, 32..63 sqs
    float v = lds[h][u] + lds[h+2][u];
    float* bank = ws + (blockIdx.x & (BANKS-1))*BANK_STRIDE;
    int c = h*32 + (u & 31);
    atomicAdd(bank + ((u < 32) ? (BOFF_S64S + c) : (BOFF_S64Q + c)), v);
  }
}

// w2 = relu(bn64(w_pre)) @ Ww1^T + bw1 via MFMA. Wave per 16 tiles.
// A-frag: lane holds rb[row r16][ch g*8+j] (chunk0) / +32 (chunk1).
// B-frag: lane holds Ww1[o=(r16&7)][same ch]. D: col=r16 (o), row=g*4+reg.
__global__ __launch_bounds__(256) void k_w2(const int* __restrict__ idx,
    const ushort_t* __restrict__ xqh, const ushort_t* __restrict__ xkh,
    const float* __restrict__ pr1, const float* __restrict__ f3,
    const float* __restrict__ f64, const float* __restrict__ Wp2,
    const float* __restrict__ bp2, const float* __restrict__ Ww1,
    const float* __restrict__ bw1, float* __restrict__ w2o,
    float* __restrict__ ws)
{
  int lane = threadIdx.x & 63;
  int r16 = lane & 15, g = lane >> 4;
  int oc = r16 & 7;
  int t0 = __builtin_amdgcn_readfirstlane((blockIdx.x*4 + (threadIdx.x >> 6)) * 16);

  float sc30=f3[0], sc31=f3[1], sc32=f3[2], sh30=f3[3], sh31=f3[4], sh32=f3[5];
  float wpaL[8],wpbL[8],wpcL[8],bpL[8],bscL[8],bshL[8];
  float wpaH[8],wpbH[8],wpcH[8],bpH[8],bscH[8],bshH[8];
#pragma unroll
  for (int j = 0; j < 8; j++){
    int cL = g*8 + j, cH = cL + 32;
    wpaL[j]=Wp2[cL*3+0]; wpbL[j]=Wp2[cL*3+1]; wpcL[j]=Wp2[cL*3+2];
    bpL[j]=bp2[cL]; bscL[j]=f64[cL]; bshL[j]=f64[64+cL];
    wpaH[j]=Wp2[cH*3+0]; wpbH[j]=Wp2[cH*3+1]; wpcH[j]=Wp2[cH*3+2];
    bpH[j]=bp2[cH]; bscH[j]=f64[cH]; bshH[j]=f64[64+cH];
  }
  bf16x8 bf0, bf1;
#pragma unroll
  for (int j = 0; j < 8; j++){
    bf0[j] = (short)f2bf(Ww1[oc*CH + g*8 + j]);
    bf1[j] = (short)f2bf(Ww1[oc*CH + 32 + g*8 + j]);
  }
  float bwv = bw1[oc];

  float SB = 0.f, SQ = 0.f;

  int tile = t0;
  int iv   = idx[tile*16 + r16];
  float a0 = pr1[(size_t)(tile*16+r16)*3+0];
  float a1 = pr1[(size_t)(tile*16+r16)*3+1];
  float a2 = pr1[(size_t)(tile*16+r16)*3+2];

#pragma unroll 1
  for (int t = 0; t < 16; t++){
    bf16x8 k0 = *(const bf16x8*)(xkh + (size_t)iv*CH + g*8);
    bf16x8 k1 = *(const bf16x8*)(xkh + (size_t)iv*CH + 32 + g*8);
    bf16x8 q0 = *(const bf16x8*)(xqh + (size_t)tile*CH + g*8);
    bf16x8 q1 = *(const bf16x8*)(xqh + (size_t)tile*CH + 32 + g*8);
    int ivn = 0; float c0=0.f, c1=0.f, c2=0.f;
    if (t < 15){
      int rn = (tile+1)*16 + r16;
      ivn = idx[rn];
      c0 = pr1[(size_t)rn*3+0]; c1 = pr1[(size_t)rn*3+1]; c2 = pr1[(size_t)rn*3+2];
    }
    float rb0 = fmaxf(fmaf(a0, sc30, sh30), 0.f);
    float rb1 = fmaxf(fmaf(a1, sc31, sh31), 0.f);
    float rb2 = fmaxf(fmaf(a2, sc32, sh32), 0.f);
    bf16x8 af0, af1;
#pragma unroll
    for (int j = 0; j < 8; j++){
      float pr2L = bpL[j] + rb0*wpaL[j] + rb1*wpbL[j] + rb2*wpcL[j];
      float wL = bf2f((ushort_t)k0[j]) - bf2f((ushort_t)q0[j]) + pr2L;
      af0[j] = (short)f2bf(fmaxf(fmaf(wL, bscL[j], bshL[j]), 0.f));
      float pr2H = bpH[j] + rb0*wpaH[j] + rb1*wpbH[j] + rb2*wpcH[j];
      float wH = bf2f((ushort_t)k1[j]) - bf2f((ushort_t)q1[j]) + pr2H;
      af1[j] = (short)f2bf(fmaxf(fmaf(wH, bscH[j], bshH[j]), 0.f));
    }
    f32x4 d = {0.f, 0.f, 0.f, 0.f};
    d = __builtin_amdgcn_mfma_f32_16x16x32_bf16(af0, bf0, d, 0, 0, 0);
    d = __builtin_amdgcn_mfma_f32_16x16x32_bf16(af1, bf1, d, 0, 0, 0);
    int row0 = tile*16;
    float dv0 = d[0]+bwv, dv1 = d[1]+bwv, dv2 = d[2]+bwv, dv3 = d[3]+bwv;
    if (r16 < 8){
      w2o[(size_t)(row0 + g*4 + 0)*8 + r16] = dv0;
      w2o[(size_t)(row0 + g*4 + 1)*8 + r16] = dv1;
      w2o[(size_t)(row0 + g*4 + 2)*8 + r16] = dv2;
      w2o[(size_t)(row0 + g*4 + 3)*8 + r16] = dv3;
    }
    SB += dv0+dv1+dv2+dv3;
    SQ += dv0*dv0 + dv1*dv1 + dv2*dv2 + dv3*dv3;
    tile++; iv = ivn; a0 = c0; a1 = c1; a2 = c2;
  }
  SB += __shfl_xor(SB, 16); SB += __shfl_xor(SB, 32);
  SQ += __shfl_xor(SQ, 16); SQ += __shfl_xor(SQ, 32);
  if (lane < 8){
    float* bank = ws + (blockIdx.x & (BANKS-1))*BANK_STRIDE;
    atomicAdd(bank + BOFF_S8S + lane, SB);
    atomicAdd(bank + BOFF_S8Q + lane, SQ);
  }
}

// final: w3 = relu(bn8(w2)) @ Ww2^T + bw2 ; softmax over 16 neighbors ;
// out = sum_j (xv+p_r2)*w. (round-4 form: uniform loads, no LDS in loop)
__global__ __launch_bounds__(256) void k_out(const int* __restrict__ idx,
    const ushort_t* __restrict__ xvh, const float* __restrict__ pr1,
    const float* __restrict__ w2, const float* __restrict__ f3,
    const float* __restrict__ f8, const float* __restrict__ Wp2,
    const float* __restrict__ bp2, const float* __restrict__ Ww2,
    const float* __restrict__ bw2, float* __restrict__ out)
{
  int lane = threadIdx.x & 63, wv = threadIdx.x >> 6;
  int n = __builtin_amdgcn_readfirstlane(blockIdx.x*4 + wv);
  int cp = lane & 7;
  int jg = lane >> 3;

  int iv[16]; float a0[16], a1[16], a2[16];
#pragma unroll
  for (int j = 0; j < 16; j++){
    int r = n*NSAMP + j;
    iv[j] = idx[r];
    a0[j] = pr1[(size_t)r*3+0];
    a1[j] = pr1[(size_t)r*3+1];
    a2[j] = pr1[(size_t)r*3+2];
  }
  ushort_t xvv[16];
#pragma unroll
  for (int j = 0; j < 16; j++) xvv[j] = xvh[(size_t)iv[j]*CH + lane];

  float wpa = Wp2[lane*3+0], wpb = Wp2[lane*3+1], wpc = Wp2[lane*3+2];
  float bp  = bp2[lane];
  float ww2_[8];
#pragma unroll
  for (int k = 0; k < 8; k++) ww2_[k] = Ww2[cp*8 + k];
  float bw = bw2[cp];
  float sc8[8], sh8[8];
#pragma unroll
  for (int k = 0; k < 8; k++){ sc8[k]=f8[k]; sh8[k]=f8[8+k]; }
  float sc30=f3[0], sc31=f3[1], sc32=f3[2], sh30=f3[3], sh31=f3[4], sh32=f3[5];

  const float4* ra  = (const float4*)(w2 + ((size_t)n*NSAMP + jg)*8);
  const float4* rbp = (const float4*)(w2 + ((size_t)n*NSAMP + jg + 8)*8);
  float4 A0 = ra[0],  A1 = ra[1];
  float4 B0 = rbp[0], B1 = rbp[1];
  float w3a = bw, w3b = bw;
#pragma unroll
  for (int k = 0; k < 8; k++){
    float va = (k < 4) ? ((k==0)?A0.x:(k==1)?A0.y:(k==2)?A0.z:A0.w)
                       : ((k==4)?A1.x:(k==5)?A1.y:(k==6)?A1.z:A1.w);
    float vb = (k < 4) ? ((k==0)?B0.x:(k==1)?B0.y:(k==2)?B0.z:B0.w)
                       : ((k==4)?B1.x:(k==5)?B1.y:(k==6)?B1.z:B1.w);
    float rba = fmaxf(va*sc8[k]+sh8[k], 0.0f);
    float rbb = fmaxf(vb*sc8[k]+sh8[k], 0.0f);
    w3a += rba * ww2_[k];
    w3b += rbb * ww2_[k];
  }

  float m = fmaxf(w3a, w3b);
#pragma unroll
  for (int mask = 8; mask <= 32; mask <<= 1) m = fmaxf(m, __shfl_xor(m, mask));
  float ea = expf(w3a - m), eb = expf(w3b - m);
  float ssum = ea + eb;
#pragma unroll
  for (int mask = 8; mask <= 32; mask <<= 1) ssum += __shfl_xor(ssum, mask);
  float inv = 1.0f / ssum;
  ea *= inv; eb *= inv;

  float oacc = 0.0f;
#pragma unroll
  for (int j = 0; j < NSAMP; j++){
    float wn = __shfl(j < 8 ? ea : eb, ((j & 7) << 3) | cp);
    float rb0 = fmaxf(fmaf(a0[j], sc30, sh30), 0.0f);
    float rb1 = fmaxf(fmaf(a1[j], sc31, sh31), 0.0f);
    float rb2 = fmaxf(fmaf(a2[j], sc32, sh32), 0.0f);
    float pr2v = bp + rb0*wpa + rb1*wpb + rb2*wpc;
    oacc += (bf2f(xvv[j]) + pr2v) * wn;
  }
  out[(size_t)n*CH + lane] = oacc;
}

extern "C" void kernel_launch(void* const* d_in, const int* in_sizes, int n_in,
                              void* d_out, int out_size, void* d_ws, size_t ws_size,
                              hipStream_t stream)
{
  const float* p    = (const float*)d_in[0];
  const float* x    = (const float*)d_in[1];
  const int*   idx  = (const int*)d_in[2];
  const float* Wq   = (const float*)d_in[3];
  const float* bq   = (const float*)d_in[4];
  const float* Wk   = (const float*)d_in[5];
  const float* bk   = (const float*)d_in[6];
  const float* Wv   = (const float*)d_in[7];
  const float* bv   = (const float*)d_in[8];
  const float* Wp1  = (const float*)d_in[9];
  const float* bp1  = (const float*)d_in[10];
  const float* gp   = (const float*)d_in[11];
  const float* betap= (const float*)d_in[12];
  const float* Wp2  = (const float*)d_in[13];
  const float* bp2  = (const float*)d_in[14];
  const float* gw1  = (const float*)d_in[15];
  const float* betaw1=(const float*)d_in[16];
  const float* Ww1  = (const float*)d_in[17];
  const float* bw1  = (const float*)d_in[18];
  const float* gw2  = (const float*)d_in[19];
  const float* betaw2=(const float*)d_in[20];
  const float* Ww2  = (const float*)d_in[21];
  const float* bw2  = (const float*)d_in[22];
  float* ws  = (float*)d_ws;
  float* out = (float*)d_out;

  ushort_t* xqh = (ushort_t*)(ws + OFF_XQH);
  ushort_t* xkh = (ushort_t*)(ws + OFF_XKH);
  ushort_t* xvh = (ushort_t*)(ws + OFF_XVH);

  k_zero<<<dim3(1), dim3(256), 0, stream>>>(ws);
  k_proj<<<dim3(NPTS*8/256, 3), dim3(256), 0, stream>>>(x, Wq,bq, Wk,bk, Wv,bv,
      xqh, xkh, xvh);
  k_pr1<<<dim3(1024), dim3(256), 0, stream>>>(p, idx, Wp1, bp1, ws);
  k_finalize<<<dim3(1), dim3(64), 0, stream>>>(ws, ws+OFF_F3, gp, betap,
      3, BOFF_S3S, BOFF_S3S+3);
  k_stats64<<<dim3(4096), dim3(256), 0, stream>>>(idx, xqh, xkh,
      ws+OFF_PR1, ws+OFF_F3, Wp2, bp2, ws);
  k_finalize<<<dim3(1), dim3(64), 0, stream>>>(ws, ws+OFF_F64, gw1, betaw1,
      64, BOFF_S64S, BOFF_S64Q);
  k_w2<<<dim3(1024), dim3(256), 0, stream>>>(idx, xqh, xkh, ws+OFF_PR1,
      ws+OFF_F3, ws+OFF_F64, Wp2, bp2, Ww1, bw1, ws+OFF_W2, ws);
  k_finalize<<<dim3(1), dim3(64), 0, stream>>>(ws, ws+OFF_F8, gw2, betaw2,
      8, BOFF_S8S, BOFF_S8Q);
  k_out<<<dim3(NPTS/4), dim3(256), 0, stream>>>(idx, xvh, ws+OFF_PR1, ws+OFF_W2,
      ws+OFF_F3, ws+OFF_F8, Wp2, bp2, Ww2, bw2, out);
}